// Round 9
// baseline (560.176 us; speedup 1.0000x reference)
//
#include <hip/hip_runtime.h>

#define IN_SIZE 256
#define OUT_SIZE 64
#define N_NODES 512
#define FAN_IN 32
#define T_DIM 2048
#define D_DIM 832
#define TOTAL_EDGE 16384
#define BLK_F4 1088   // per-node: 1024 f4 butterfly pairs + 64 f4 entries
#define MAX_ENT 64
#define THRESH -20.0f

// DPP wave64 sum (lane 63 ends with total) — validated rounds 3..8
template <int CTRL, int RM>
__device__ __forceinline__ float dppadd(float v) {
  int m = __builtin_amdgcn_update_dpp(0, __float_as_int(v), CTRL, RM, 0xf, true);
  return v + __int_as_float(m);
}
__device__ __forceinline__ void wave_sum2(float& a, float& b) {
  a = dppadd<0x111, 0xf>(a); b = dppadd<0x111, 0xf>(b);
  a = dppadd<0x112, 0xf>(a); b = dppadd<0x112, 0xf>(b);
  a = dppadd<0x114, 0xf>(a); b = dppadd<0x114, 0xf>(b);
  a = dppadd<0x118, 0xf>(a); b = dppadd<0x118, 0xf>(b);
  a = dppadd<0x142, 0xa>(a); b = dppadd<0x142, 0xa>(b);
  a = dppadd<0x143, 0xc>(a); b = dppadd<0x143, 0xc>(b);
}
__device__ __forceinline__ float rl63(float v) {
  return __int_as_float(__builtin_amdgcn_readlane(__float_as_int(v), 63));
}

// ---------------------------------------------------------------------------
// Block build (FUSED): per node —
//  phase 0: compute K/V for all 2047 shifted timesteps directly from actives
//           (lane-per-fanin gather + shuffle reduce; replaces kv_kernel)
//  phase 1: kmax/kmin, 64-bin bucket sort ascending
//  phase 2: butterfly pairs B[p]=(asc_k,asc_v,desc_k,desc_v), entries,
//           meta (kmax/kmin/cnt + 6 skip boundaries + d1 adj), base dot.
// ---------------------------------------------------------------------------
__global__ __launch_bounds__(256) void block_kernel(
    const float* __restrict__ x, const float* __restrict__ actives,
    const int* __restrict__ in_idxs, const float* __restrict__ weights,
    float4* __restrict__ blk, float4* __restrict__ meta_g,
    float4* __restrict__ Qb) {
  __shared__ float2 skv[T_DIM], sbk[T_DIM];
  __shared__ int s_idx[FAN_IN];
  __shared__ float s_w1[FAN_IN], s_w2[FAN_IN];
  __shared__ int hist[64];
  __shared__ float smx[4], smn[4];
  __shared__ float sadj[3];
  __shared__ float4 sEnt[MAX_ENT];
  __shared__ int ecnt;
  const int node = blockIdx.x, tid = threadIdx.x;
  if (tid == 0) ecnt = 0;
  if (tid < FAN_IN) {
    int g = node * FAN_IN + tid;
    s_idx[tid] = in_idxs[g];
    const float* wp = weights + (size_t)g * 3;
    s_w1[tid] = wp[1];
    s_w2[tid] = wp[2];
  }
  __syncthreads();

  // ---- phase 0: K/V gather. 4 waves x 2 t per pass (lane-per-fanin).
  const int lane = tid & 63, wid = tid >> 6;
  const int f = lane & 31, tsub = lane >> 5;
  const int idxf = s_idx[f];
  const float w1 = s_w1[f], w2 = s_w2[f];
  float mx = -3.4e38f, mn = 3.4e38f;
  for (int base = 0; base < T_DIM; base += 8) {
    int t = base + wid * 2 + tsub;
    float a = (t < T_DIM - 1) ? actives[(size_t)(t + 1) * D_DIM + idxf] : 0.f;
    float k = w1 * a, v = w2 * a;
#pragma unroll
    for (int off = 1; off < 32; off <<= 1) {
      k += __shfl_xor(k, off);
      v += __shfl_xor(v, off);
    }
    if (f == 0) {
      skv[t] = make_float2(k, v);
      if (t < T_DIM - 1) { mx = fmaxf(mx, k); mn = fminf(mn, k); }
    }
  }
  // wave reduce (non-writer lanes hold neutral values)
#pragma unroll
  for (int off = 32; off > 0; off >>= 1) {
    mx = fmaxf(mx, __shfl_xor(mx, off));
    mn = fminf(mn, __shfl_xor(mn, off));
  }
  if (lane == 0) { smx[wid] = mx; smn[wid] = mn; }
  if (tid < 64) hist[tid] = 0;
  __syncthreads();

  // ---- phase 1: bucket sort ascending
  float kmax = fmaxf(fmaxf(smx[0], smx[1]), fmaxf(smx[2], smx[3]));
  float kmin = fminf(fminf(smn[0], smn[1]), fminf(smn[2], smn[3]));
  float invbw = 64.0f / (kmax - kmin);
#pragma unroll
  for (int j = 0; j < 8; ++j) {
    int t = j * 256 + tid;
    if (t < 2047) {
      int b = (int)((skv[t].x - kmin) * invbw);
      b = b < 0 ? 0 : (b > 63 ? 63 : b);
      atomicAdd(&hist[b], 1);
    }
  }
  // consumer entries: edges e with in_idxs[e]==256+node, consumer != node+1
  {
    int target = IN_SIZE + node;
    for (int e = tid; e < TOTAL_EDGE; e += 256) {
      if (in_idxs[e] == target) {
        int c = e >> 5;
        if (c != node + 1) {
          int p = atomicAdd(&ecnt, 1);
          if (p < MAX_ENT) {
            const float* wp = weights + (size_t)e * 3;
            sEnt[p] = make_float4(__int_as_float(c), wp[0], wp[1], wp[2]);
          }
        }
      }
    }
  }
  __syncthreads();
  if (tid < 64) {
    int v = hist[tid];
    int incl = v;
#pragma unroll
    for (int d = 1; d < 64; d <<= 1) {
      int u = __shfl_up(incl, d);
      if (tid >= d) incl += u;
    }
    hist[tid] = incl - v;  // exclusive prefix -> cursor
  }
  __syncthreads();
#pragma unroll
  for (int j = 0; j < 8; ++j) {
    int t = j * 256 + tid;
    if (t < 2047) {
      int b = (int)((skv[t].x - kmin) * invbw);
      b = b < 0 ? 0 : (b > 63 ? 63 : b);
      int p = atomicAdd(&hist[b], 1);
      sbk[p] = skv[t];
    }
  }
  // base dot + d1 patch weights (lanes < 32 of wave 0)
  if (tid < 32) {
    int g = node * FAN_IN + tid;
    int idx = in_idxs[g];
    const float* wp = weights + (size_t)g * 3;
    float a = (idx < IN_SIZE) ? x[idx] : 0.f;
    bool d1 = (idx >= IN_SIZE) && (idx - IN_SIZE == node - 1);
    float p0 = a * wp[0], p1 = a * wp[1], p2 = a * wp[2];
    float p3 = d1 ? wp[0] : 0.f, p4 = d1 ? wp[1] : 0.f, p5 = d1 ? wp[2] : 0.f;
#pragma unroll
    for (int off = 16; off > 0; off >>= 1) {
      p0 += __shfl_xor(p0, off); p1 += __shfl_xor(p1, off);
      p2 += __shfl_xor(p2, off); p3 += __shfl_xor(p3, off);
      p4 += __shfl_xor(p4, off); p5 += __shfl_xor(p5, off);
    }
    if (tid == 0) {
      Qb[node] = make_float4(p0, p1, p2, 0.f);
      sadj[0] = p3; sadj[1] = p4; sadj[2] = p5;
    }
  }
  __syncthreads();  // sbk + sadj + sEnt complete

  // ---- phase 2: write block + meta
  float4* B = blk + (size_t)node * BLK_F4;
  for (int i = tid; i < 1024; i += 256) {
    float2 a = sbk[i];
    float2 d = sbk[2046 - i];
    B[i] = make_float4(a.x, a.y, d.x, d.y);
  }
  int cnt = ecnt < MAX_ENT ? ecnt : MAX_ENT;
  if (tid < MAX_ENT)
    B[1024 + tid] = (tid < cnt) ? sEnt[tid] : make_float4(0.f, 0.f, 0.f, 0.f);
  if (tid == 0)
    meta_g[3 * node + 0] =
        make_float4(kmax, kmin, __int_as_float(cnt), sbk[64].x);
  if (tid == 1)
    meta_g[3 * node + 1] =
        make_float4(sbk[1982].x, sbk[256].x, sbk[1790].x, sbk[512].x);
  if (tid == 2)
    meta_g[3 * node + 2] = make_float4(sbk[1534].x, sadj[0], sadj[1], sadj[2]);
}

// ---------------------------------------------------------------------------
// Sequential scan: 1 wave, zero barriers. Always-set per node is TINY:
// chunk0 (64 butterfly pairs = 1 f4/lane) + entries (1 f4/lane), carried in a
// depth-4 register pipeline (8 f4 total — too small for the compiler to
// sink). Tails c1/c2/c3 load on demand under exact skip predicates, issued
// right after m so their latency overlaps chunk0 compute. Meta + pending
// dots in LDS.
// ---------------------------------------------------------------------------
__global__ __launch_bounds__(64, 1) void seq_kernel(
    const float4* __restrict__ Qb, const float4* __restrict__ meta_g,
    const float4* __restrict__ blk, float* __restrict__ out) {
  __shared__ float4 sMeta[N_NODES][3];  // 24 KB
  __shared__ float4 sQKV[N_NODES];      // 8 KB pending (q,kl,vl) dots
  __shared__ float souts[OUT_SIZE];
  const int lane = threadIdx.x;
  for (int n = lane; n < N_NODES; n += 64) {
    sMeta[n][0] = meta_g[3 * n + 0];
    sMeta[n][1] = meta_g[3 * n + 1];
    sMeta[n][2] = meta_g[3 * n + 2];
    sQKV[n] = Qb[n];
  }
  // single wave: in-order DS ops, no barrier needed anywhere

  // depth-4 pipeline: chunk0 + entries for nodes ix..ix+3
  float4 c0s0, c0s1, c0s2, c0s3, ens0, ens1, ens2, ens3;
  c0s0 = blk[0 * BLK_F4 + lane];          ens0 = blk[0 * BLK_F4 + 1024 + lane];
  c0s1 = blk[1 * BLK_F4 + lane];          ens1 = blk[1 * BLK_F4 + 1024 + lane];
  c0s2 = blk[2 * BLK_F4 + lane];          ens2 = blk[2 * BLK_F4 + 1024 + lane];
  c0s3 = blk[3 * BLK_F4 + lane];          ens3 = blk[3 * BLK_F4 + 1024 + lane];

  float4 qkv = Qb[0];  // node 0: no d1 predecessor -> exact
  float4 mC0 = sMeta[0][0], mC1 = sMeta[0][1], mC2 = sMeta[0][2];

  auto step = [&](int ix, float4& C0, float4& ENT) {
    int ixn = (ix + 1 < N_NODES) ? ix + 1 : N_NODES - 1;
    int ixp = (ix + 4 < N_NODES) ? ix + 4 : N_NODES - 1;
    // early LDS pre-reads for node ix+1 (d1 term patched at rotate)
    float4 rawn = sQKV[ixn];
    float4 mN0 = sMeta[ixn][0], mN1 = sMeta[ixn][1], mN2 = sMeta[ixn][2];

    float q = qkv.x, kl = qkv.y, vl = qkv.z;
    int cnt = __float_as_int(mC0.z);
    float m = fmaxf(fmaxf(q * mC0.x, q * mC0.y), q * kl);
    // exact skip predicates: dropped-set max logit vs m
    bool p1 = fmaxf(q * mC0.w, q * mC1.x) - m >= THRESH;   // need pairs 64..255
    bool p2 = p1 && (fmaxf(q * mC1.y, q * mC1.z) - m >= THRESH);  // 256..511
    bool p3 = p2 && (fmaxf(q * mC1.w, q * mC2.x) - m >= THRESH);  // 512..1023

    // on-demand tail loads, issued EARLY (overlap chunk0 compute)
    const float4* B = blk + (size_t)ix * BLK_F4;
    float4 t1[3], t2[4], t3[8];
    if (p1) {
#pragma unroll
      for (int t = 0; t < 3; ++t) t1[t] = B[64 + 64 * t + lane];
    }
    if (p2) {
#pragma unroll
      for (int t = 0; t < 4; ++t) t2[t] = B[256 + 64 * t + lane];
    }
    if (p3) {
#pragma unroll
      for (int t = 0; t < 8; ++t) t3[t] = B[512 + 64 * t + lane];
    }

    float el = __expf(q * kl - m);
    // chunk0: 64 pairs (top-64 + bottom-64 k's); wrong-direction side
    // underflows to exp = 0
    float w0 = __expf(fmaf(q, C0.x, -m));
    float w1 = __expf(fmaf(q, C0.z, -m));
    float sw = w0 + w1;
    float swv = fmaf(w0, C0.y, w1 * C0.w);
    if (p1) {
#pragma unroll
      for (int t = 0; t < 3; ++t) {
        float a0 = __expf(fmaf(q, t1[t].x, -m));
        float a1 = __expf(fmaf(q, t1[t].z, -m));
        sw += a0 + a1;
        swv = fmaf(a0, t1[t].y, fmaf(a1, t1[t].w, swv));
      }
    }
    if (p2) {
#pragma unroll
      for (int t = 0; t < 4; ++t) {
        float a0 = __expf(fmaf(q, t2[t].x, -m));
        float a1 = __expf(fmaf(q, t2[t].z, -m));
        sw += a0 + a1;
        swv = fmaf(a0, t2[t].y, fmaf(a1, t2[t].w, swv));
      }
    }
    if (p3) {
#pragma unroll
      for (int t = 0; t < 8; ++t) {
        float a0 = __expf(fmaf(q, t3[t].x, -m));
        float a1 = __expf(fmaf(q, t3[t].z, -m));
        if (t == 7 && lane == 63) a1 = 0.f;  // pair 1023 desc = median dup
        sw += a0 + a1;
        swv = fmaf(a0, t3[t].y, fmaf(a1, t3[t].w, swv));
      }
    }

    // chunk0 consumed -> refill with node ix+4 (tiny, stays hoisted)
    C0 = blk[(size_t)ixp * BLK_F4 + lane];

    // reduce + finish
    wave_sum2(sw, swv);
    float S = rl63(sw) + el;
    float SV = fmaf(el, vl, rl63(swv));
    float z = SV * __builtin_amdgcn_rcpf(S);
    float eo = __expf(2.f * z);
    float o = 1.f - 2.f * __builtin_amdgcn_rcpf(eo + 1.f);
    if (lane == 0 && ix >= N_NODES - OUT_SIZE)
      souts[ix - (N_NODES - OUT_SIZE)] = o;

    // scatter o into pending dots (d>=2 consumers; never targets ix+1)
    if (lane < cnt) {
      int n = __float_as_int(ENT.x);
      atomicAdd(&sQKV[n].x, o * ENT.y);
      atomicAdd(&sQKV[n].y, o * ENT.z);
      atomicAdd(&sQKV[n].z, o * ENT.w);
    }
    ENT = blk[(size_t)ixp * BLK_F4 + 1024 + lane];  // refill after use

    // rotate: d1 register patch (adj = mN2.yzw) completes node ix+1's dot
    qkv = make_float4(fmaf(o, mN2.y, rawn.x), fmaf(o, mN2.z, rawn.y),
                      fmaf(o, mN2.w, rawn.z), 0.f);
    mC0 = mN0; mC1 = mN1; mC2 = mN2;
  };

  for (int ix = 0; ix < N_NODES; ix += 4) {
    step(ix + 0, c0s0, ens0);
    step(ix + 1, c0s1, ens1);
    step(ix + 2, c0s2, ens2);
    step(ix + 3, c0s3, ens3);
  }
  out[lane] = souts[lane];
}

// ---------------------------------------------------------------------------
extern "C" void kernel_launch(void* const* d_in, const int* in_sizes, int n_in,
                              void* d_out, int out_size, void* d_ws,
                              size_t ws_size, hipStream_t stream) {
  const float* x = (const float*)d_in[0];
  const float* actives = (const float*)d_in[1];
  const float* weights = (const float*)d_in[2];
  const int* in_idxs = (const int*)d_in[3];
  float* out = (float*)d_out;

  // workspace (~9.0 MB): blk | meta_g | Qb
  char* ws = (char*)d_ws;
  float4* blk = (float4*)ws;  // 512 * 1088 * 16 = 8,912,896 B
  size_t off = (size_t)N_NODES * BLK_F4 * 16;
  float4* meta_g = (float4*)(ws + off); off += (size_t)N_NODES * 3 * 16;
  float4* Qb = (float4*)(ws + off);

  block_kernel<<<N_NODES, 256, 0, stream>>>(x, actives, in_idxs, weights, blk,
                                            meta_g, Qb);
  seq_kernel<<<1, 64, 0, stream>>>(Qb, meta_g, blk, out);
}

// Round 10
// 257.436 us; speedup vs baseline: 2.1760x; 2.1760x over previous
//
#include <hip/hip_runtime.h>

#define IN_SIZE 256
#define OUT_SIZE 64
#define N_NODES 512
#define FAN_IN 32
#define T_DIM 2048
#define D_DIM 832
#define TOTAL_EDGE 16384
#define BLK_F4 1088   // per-node: 1024 f4 butterfly pairs + 64 f4 entries
#define MAX_ENT 64
#define THRESH -20.0f

// DPP wave64 sum (lane 63 ends with total) — validated rounds 3..9
template <int CTRL, int RM>
__device__ __forceinline__ float dppadd(float v) {
  int m = __builtin_amdgcn_update_dpp(0, __float_as_int(v), CTRL, RM, 0xf, true);
  return v + __int_as_float(m);
}
__device__ __forceinline__ void wave_sum2(float& a, float& b) {
  a = dppadd<0x111, 0xf>(a); b = dppadd<0x111, 0xf>(b);
  a = dppadd<0x112, 0xf>(a); b = dppadd<0x112, 0xf>(b);
  a = dppadd<0x114, 0xf>(a); b = dppadd<0x114, 0xf>(b);
  a = dppadd<0x118, 0xf>(a); b = dppadd<0x118, 0xf>(b);
  a = dppadd<0x142, 0xa>(a); b = dppadd<0x142, 0xa>(b);
  a = dppadd<0x143, 0xc>(a); b = dppadd<0x143, 0xc>(b);
}
__device__ __forceinline__ float rl63(float v) {
  return __int_as_float(__builtin_amdgcn_readlane(__float_as_int(v), 63));
}

// ---------------------------------------------------------------------------
// KV build (t-major, rows staged in LDS) — r7's proven version.
// Writes (k,v) t-order into blk KV area; slot 2047 = 0.
// ---------------------------------------------------------------------------
__global__ __launch_bounds__(256) void kv_kernel(
    const float* __restrict__ actives, const int* __restrict__ in_idxs,
    const float* __restrict__ weights, float2* __restrict__ KVd) {
  __shared__ float rows[8][833];
  __shared__ int s_idx[64 * FAN_IN];
  __shared__ float2 s_w[64 * FAN_IN];
  int tid = threadIdx.x;
  int tb = blockIdx.x * 8;
  for (int i = tid; i < 8 * D_DIM; i += 256) {
    int r = i / D_DIM, c = i - r * D_DIM;
    int t = tb + r;
    rows[r][c] = (t < T_DIM - 1) ? actives[(size_t)(t + 1) * D_DIM + c] : 0.f;
  }
  int tl = tid & 7, ng = tid >> 3;
  for (int tile = 0; tile < 8; ++tile) {
    __syncthreads();
    int n0 = tile * 64;
    for (int i = tid; i < 64 * FAN_IN; i += 256) {
      int g = n0 * FAN_IN + i;
      s_idx[i] = in_idxs[g];
      const float* wp = weights + (size_t)g * 3;
      s_w[i] = make_float2(wp[1], wp[2]);
    }
    __syncthreads();
#pragma unroll
    for (int it = 0; it < 2; ++it) {
      int nl = ng + 32 * it;
      const int* ip = &s_idx[nl * FAN_IN];
      const float2* wp = &s_w[nl * FAN_IN];
      float k = 0.f, v = 0.f;
#pragma unroll 8
      for (int f = 0; f < FAN_IN; ++f) {
        float a = rows[tl][ip[f]];
        float2 w = wp[f];
        k = fmaf(w.x, a, k);
        v = fmaf(w.y, a, v);
      }
      KVd[(size_t)(n0 + nl) * (2 * BLK_F4) + tb + tl] = make_float2(k, v);
    }
  }
}

// ---------------------------------------------------------------------------
// Block build: bucket-sort k ascending -> butterfly pairs
// B[p]=(asc_k,asc_v,desc_k,desc_v) p<1024; entries at B[1024..1087]
// (consumers c > node ONLY — dead edges c<=node excluded: with level-parallel
// execution their scatter would race a same-level read; reference reads 0).
// meta (kmax/kmin/cnt + skip bounds at 64-pair chunk0) -> meta_g; base -> Qb.
// ---------------------------------------------------------------------------
__global__ __launch_bounds__(256) void block_kernel(
    const float* __restrict__ x, const int* __restrict__ in_idxs,
    const float* __restrict__ weights, float4* __restrict__ blk,
    float4* __restrict__ meta_g, float4* __restrict__ Qb) {
  __shared__ float2 skv[T_DIM], sbk[T_DIM];
  __shared__ int hist[64];
  __shared__ float smx[4], smn[4];
  __shared__ float4 sEnt[MAX_ENT];
  __shared__ int ecnt;
  int node = blockIdx.x, tid = threadIdx.x;
  if (tid == 0) ecnt = 0;
  const float2* src = (const float2*)(blk + (size_t)node * BLK_F4);
  float mx = -3.4e38f, mn = 3.4e38f;
#pragma unroll
  for (int j = 0; j < 8; ++j) {
    int t = j * 256 + tid;
    float2 kv = (t < 2047) ? src[t] : make_float2(0.f, 0.f);
    skv[t] = kv;
    if (t < 2047) { mx = fmaxf(mx, kv.x); mn = fminf(mn, kv.x); }
  }
  if (tid < 64) hist[tid] = 0;
#pragma unroll
  for (int off = 32; off > 0; off >>= 1) {
    mx = fmaxf(mx, __shfl_xor(mx, off));
    mn = fminf(mn, __shfl_xor(mn, off));
  }
  if ((tid & 63) == 0) { smx[tid >> 6] = mx; smn[tid >> 6] = mn; }
  __syncthreads();
  float kmax = fmaxf(fmaxf(smx[0], smx[1]), fmaxf(smx[2], smx[3]));
  float kmin = fminf(fminf(smn[0], smn[1]), fminf(smn[2], smn[3]));
  float invbw = 64.0f / (kmax - kmin);
#pragma unroll
  for (int j = 0; j < 8; ++j) {
    int t = j * 256 + tid;
    if (t < 2047) {
      int b = (int)((skv[t].x - kmin) * invbw);
      b = b < 0 ? 0 : (b > 63 ? 63 : b);
      atomicAdd(&hist[b], 1);
    }
  }
  // consumer entries: edges e with in_idxs[e]==256+node and consumer > node
  {
    int target = IN_SIZE + node;
    for (int e = tid; e < TOTAL_EDGE; e += 256) {
      if (in_idxs[e] == target) {
        int c = e >> 5;
        if (c > node) {
          int p = atomicAdd(&ecnt, 1);
          if (p < MAX_ENT) {
            const float* wp = weights + (size_t)e * 3;
            sEnt[p] = make_float4(__int_as_float(c), wp[0], wp[1], wp[2]);
          }
        }
      }
    }
  }
  __syncthreads();
  if (tid < 64) {
    int v = hist[tid];
    int incl = v;
#pragma unroll
    for (int d = 1; d < 64; d <<= 1) {
      int u = __shfl_up(incl, d);
      if (tid >= d) incl += u;
    }
    hist[tid] = incl - v;
  }
  if (tid == 0) sbk[2047] = make_float2(0.f, 0.f);
  __syncthreads();
#pragma unroll
  for (int j = 0; j < 8; ++j) {
    int t = j * 256 + tid;
    if (t < 2047) {
      int b = (int)((skv[t].x - kmin) * invbw);
      b = b < 0 ? 0 : (b > 63 ? 63 : b);
      int p = atomicAdd(&hist[b], 1);
      sbk[p] = skv[t];
    }
  }
  // base dot from x (node inputs >= IN_SIZE contribute via scatters)
  if (tid < 32) {
    int g = node * FAN_IN + tid;
    int idx = in_idxs[g];
    const float* wp = weights + (size_t)g * 3;
    float a = (idx < IN_SIZE) ? x[idx] : 0.f;
    float p0 = a * wp[0], p1 = a * wp[1], p2 = a * wp[2];
#pragma unroll
    for (int off = 16; off > 0; off >>= 1) {
      p0 += __shfl_xor(p0, off);
      p1 += __shfl_xor(p1, off);
      p2 += __shfl_xor(p2, off);
    }
    if (tid == 0) Qb[node] = make_float4(p0, p1, p2, 0.f);
  }
  __syncthreads();
  float4* B = blk + (size_t)node * BLK_F4;
  for (int i = tid; i < 1024; i += 256) {
    float2 a = sbk[i];
    float2 d = sbk[2046 - i];
    B[i] = make_float4(a.x, a.y, d.x, d.y);
  }
  int cnt = ecnt < MAX_ENT ? ecnt : MAX_ENT;
  if (tid < MAX_ENT)
    B[1024 + tid] = (tid < cnt) ? sEnt[tid] : make_float4(0.f, 0.f, 0.f, 0.f);
  if (tid == 0)
    meta_g[3 * node + 0] =
        make_float4(kmax, kmin, __int_as_float(cnt), sbk[64].x);
  if (tid == 1)
    meta_g[3 * node + 1] =
        make_float4(sbk[1982].x, sbk[256].x, sbk[1790].x, sbk[512].x);
  if (tid == 2)
    meta_g[3 * node + 2] = make_float4(sbk[1534].x, 0.f, 0.f, 0.f);
}

// ---------------------------------------------------------------------------
// Level sweep: 1 block x 1024 thr (16 waves). Prologue computes DAG levels
// (parallel relaxation, monotone, LDS) + counting sort. Main loop: one level
// per iteration; wave w processes node sOrder[start+w] with chunk0/entries/
// meta prefetched BEFORE the previous barrier (static addresses); tails load
// on demand under exact skip predicates (stall overlaps across waves).
// Scatter into sQKV via LDS atomics; one barrier per level.
// ---------------------------------------------------------------------------
__global__ __launch_bounds__(1024) void sweep_kernel(
    const int* __restrict__ in_idxs, const float4* __restrict__ Qb,
    const float4* __restrict__ meta_g, const float4* __restrict__ blk,
    float* __restrict__ out) {
  __shared__ float4 sQKV[N_NODES];
  __shared__ float4 sMeta[N_NODES][3];
  __shared__ int sLevel[N_NODES];
  __shared__ int sOrder[N_NODES];
  __shared__ int sStart[N_NODES + 1];
  __shared__ int sCur[N_NODES + 1];
  __shared__ int wtot[8];
  __shared__ int sFlag, sNlev;
  __shared__ float souts[OUT_SIZE];
  const int tid = threadIdx.x;
  const int lane = tid & 63;
  const int w = tid >> 6;

  for (int n = tid; n < N_NODES; n += 1024) {
    sQKV[n] = Qb[n];
    sMeta[n][0] = meta_g[3 * n + 0];
    sMeta[n][1] = meta_g[3 * n + 1];
    sMeta[n][2] = meta_g[3 * n + 2];
    sLevel[n] = 0;
  }
  if (tid == 0) { sFlag = 1; sNlev = 0; }
  // per-thread pred list in regs (tid < 512)
  int pidx[32];
  if (tid < N_NODES) {
    const int4* ip = (const int4*)(in_idxs + tid * FAN_IN);
#pragma unroll
    for (int j = 0; j < 8; ++j) {
      int4 v = ip[j];
      pidx[4 * j + 0] = v.x; pidx[4 * j + 1] = v.y;
      pidx[4 * j + 2] = v.z; pidx[4 * j + 3] = v.w;
    }
  }
  __syncthreads();

  // ---- level relaxation (monotone Bellman-Ford in LDS) ----
  bool again = true;
  while (again) {
    if (tid == 0) sFlag = 0;
    __syncthreads();
    bool ch = false;
    if (tid < N_NODES) {
      int nl = 0;
#pragma unroll
      for (int f = 0; f < FAN_IN; ++f) {
        int p = pidx[f] - IN_SIZE;
        if (p >= 0 && p < tid) {
          int lp = sLevel[p] + 1;
          nl = nl > lp ? nl : lp;
        }
      }
      if (nl > sLevel[tid]) { sLevel[tid] = nl; ch = true; }
    }
    if (ch) sFlag = 1;
    __syncthreads();
    again = (sFlag != 0);
  }

  // ---- counting sort by level ----
  for (int i = tid; i <= N_NODES; i += 1024) sCur[i] = 0;
  __syncthreads();
  if (tid < N_NODES) {
    atomicAdd(&sCur[sLevel[tid]], 1);
    atomicMax(&sNlev, sLevel[tid] + 1);
  }
  __syncthreads();
  int incl = 0;
  if (tid < N_NODES) {
    incl = sCur[tid];
#pragma unroll
    for (int d = 1; d < 64; d <<= 1) {
      int u = __shfl_up(incl, d);
      if ((tid & 63) >= d) incl += u;
    }
    if ((tid & 63) == 63) wtot[tid >> 6] = incl;
  }
  __syncthreads();
  if (tid < N_NODES) {
    int add = 0;
    for (int ww = 0; ww < (tid >> 6); ++ww) add += wtot[ww];
    sStart[tid + 1] = incl + add;
    if (tid == 0) sStart[0] = 0;
  }
  __syncthreads();
  for (int i = tid; i < N_NODES; i += 1024) sCur[i] = sStart[i];
  __syncthreads();
  if (tid < N_NODES) {
    int p = atomicAdd(&sCur[sLevel[tid]], 1);
    sOrder[p] = tid;
  }
  __syncthreads();

  const int nlev = sNlev;

  auto process = [&](int node, float4 C0, float4 ENT, float4 m0, float4 m1,
                     float4 m2) {
    float4 qv = sQKV[node];
    float q = qv.x, kl = qv.y, vl = qv.z;
    int cnt = __float_as_int(m0.z);
    float m = fmaxf(fmaxf(q * m0.x, q * m0.y), q * kl);
    bool p1 = fmaxf(q * m0.w, q * m1.x) - m >= THRESH;   // pairs 64..255
    bool p2 = p1 && (fmaxf(q * m1.y, q * m1.z) - m >= THRESH);  // 256..511
    bool p3 = p2 && (fmaxf(q * m1.w, q * m2.x) - m >= THRESH);  // 512..1023
    const float4* B = blk + (size_t)node * BLK_F4;
    float4 t1[3], t2[4], t3[8];
    if (p1) {
#pragma unroll
      for (int t = 0; t < 3; ++t) t1[t] = B[64 + 64 * t + lane];
    }
    if (p2) {
#pragma unroll
      for (int t = 0; t < 4; ++t) t2[t] = B[256 + 64 * t + lane];
    }
    if (p3) {
#pragma unroll
      for (int t = 0; t < 8; ++t) t3[t] = B[512 + 64 * t + lane];
    }
    float el = __expf(q * kl - m);
    float w0 = __expf(fmaf(q, C0.x, -m));
    float w1 = __expf(fmaf(q, C0.z, -m));
    float sw = w0 + w1;
    float swv = fmaf(w0, C0.y, w1 * C0.w);
    if (p1) {
#pragma unroll
      for (int t = 0; t < 3; ++t) {
        float a0 = __expf(fmaf(q, t1[t].x, -m));
        float a1 = __expf(fmaf(q, t1[t].z, -m));
        sw += a0 + a1;
        swv = fmaf(a0, t1[t].y, fmaf(a1, t1[t].w, swv));
      }
    }
    if (p2) {
#pragma unroll
      for (int t = 0; t < 4; ++t) {
        float a0 = __expf(fmaf(q, t2[t].x, -m));
        float a1 = __expf(fmaf(q, t2[t].z, -m));
        sw += a0 + a1;
        swv = fmaf(a0, t2[t].y, fmaf(a1, t2[t].w, swv));
      }
    }
    if (p3) {
#pragma unroll
      for (int t = 0; t < 8; ++t) {
        float a0 = __expf(fmaf(q, t3[t].x, -m));
        float a1 = __expf(fmaf(q, t3[t].z, -m));
        if (t == 7 && lane == 63) a1 = 0.f;  // pair 1023 desc = median dup
        sw += a0 + a1;
        swv = fmaf(a0, t3[t].y, fmaf(a1, t3[t].w, swv));
      }
    }
    wave_sum2(sw, swv);
    float S = rl63(sw) + el;
    float SV = fmaf(el, vl, rl63(swv));
    float z = SV * __builtin_amdgcn_rcpf(S);
    float eo = __expf(2.f * z);
    float o = 1.f - 2.f * __builtin_amdgcn_rcpf(eo + 1.f);
    if (lane == 0 && node >= N_NODES - OUT_SIZE)
      souts[node - (N_NODES - OUT_SIZE)] = o;
    if (lane < cnt) {
      int n = __float_as_int(ENT.x);
      atomicAdd(&sQKV[n].x, o * ENT.y);
      atomicAdd(&sQKV[n].y, o * ENT.z);
      atomicAdd(&sQKV[n].z, o * ENT.w);
    }
  };

  // prefetch level 0 assignment
  int pn = -1;
  float4 c0, ent, pm0, pm1, pm2;
  {
    int e0 = sStart[1];
    int j = 0 + w;
    if (j < e0) {
      pn = sOrder[j];
      const float4* B = blk + (size_t)pn * BLK_F4;
      c0 = B[lane];
      ent = B[1024 + lane];
      pm0 = sMeta[pn][0]; pm1 = sMeta[pn][1]; pm2 = sMeta[pn][2];
    }
  }
  __syncthreads();

  for (int L = 0; L < nlev; ++L) {
    int sL = sStart[L], eL = sStart[L + 1];
    if (pn >= 0) process(pn, c0, ent, pm0, pm1, pm2);
    // overflow nodes (level wider than 16): fully on-demand (rare)
    for (int i = sL + w + 16; i < eL; i += 16) {
      int n2 = sOrder[i];
      const float4* B = blk + (size_t)n2 * BLK_F4;
      process(n2, B[lane], B[1024 + lane], sMeta[n2][0], sMeta[n2][1],
              sMeta[n2][2]);
    }
    // prefetch next level (static addresses; sQKV deliberately NOT read)
    pn = -1;
    if (L + 1 < nlev) {
      int sN = sStart[L + 1], eN = sStart[L + 2];
      int j = sN + w;
      if (j < eN) {
        pn = sOrder[j];
        const float4* B = blk + (size_t)pn * BLK_F4;
        c0 = B[lane];
        ent = B[1024 + lane];
        pm0 = sMeta[pn][0]; pm1 = sMeta[pn][1]; pm2 = sMeta[pn][2];
      }
    }
    __syncthreads();  // level L scatters visible; level L+1 may read sQKV
  }
  if (tid < OUT_SIZE) out[tid] = souts[tid];
}

// ---------------------------------------------------------------------------
extern "C" void kernel_launch(void* const* d_in, const int* in_sizes, int n_in,
                              void* d_out, int out_size, void* d_ws,
                              size_t ws_size, hipStream_t stream) {
  const float* x = (const float*)d_in[0];
  const float* actives = (const float*)d_in[1];
  const float* weights = (const float*)d_in[2];
  const int* in_idxs = (const int*)d_in[3];
  float* out = (float*)d_out;

  // workspace (~9.0 MB): blk | meta_g | Qb
  char* ws = (char*)d_ws;
  float4* blk = (float4*)ws;  // 512 * 1088 * 16 = 8,912,896 B
  size_t off = (size_t)N_NODES * BLK_F4 * 16;
  float4* meta_g = (float4*)(ws + off); off += (size_t)N_NODES * 3 * 16;
  float4* Qb = (float4*)(ws + off);

  kv_kernel<<<T_DIM / 8, 256, 0, stream>>>(actives, in_idxs, weights,
                                           (float2*)blk);
  block_kernel<<<N_NODES, 256, 0, stream>>>(x, in_idxs, weights, blk, meta_g,
                                            Qb);
  sweep_kernel<<<1, 1024, 0, stream>>>(in_idxs, Qb, meta_g, blk, out);
}